// Round 7
// baseline (435.796 us; speedup 1.0000x reference)
//
#include <hip/hip_runtime.h>
#include <hip/hip_bf16.h>
#include <hip/hip_cooperative_groups.h>

namespace cg = cooperative_groups;

typedef __attribute__((ext_vector_type(8))) short bf16x8;
typedef __attribute__((ext_vector_type(4))) float f32x4;

__device__ inline short f2bf(float f) {
    __hip_bfloat16 h = __float2bfloat16(f);
    short s;
    __builtin_memcpy(&s, &h, 2);
    return s;
}
__device__ inline float bf2f(short s) {
    unsigned int u = ((unsigned int)(unsigned short)s) << 16;
    float f;
    __builtin_memcpy(&f, &u, 4);
    return f;
}

// async 16B global->LDS; dest must be wave-uniform base + lane*16
__device__ inline void cp16_async(const void* g, void* l) {
    __builtin_amdgcn_global_load_lds(
        (const __attribute__((address_space(1))) void*)g,
        (__attribute__((address_space(3))) void*)l, 16, 0, 0);
}

// ---------------- 128x128 MFMA core, K-step 64 via 4 m97-style panels ----------------

__device__ inline void mfma_kloop64(const short* __restrict__ A, int lda,
                                    const short* __restrict__ B, int ldb,
                                    int Kd, f32x4* acc,
                                    short* sA0, short* sA1, short* sB0, short* sB1) {
    const int tid = threadIdx.x, lane = tid & 63, wv = tid >> 6;
    const int quad = lane >> 4, lr = lane & 15;
    const int wr = (wv >> 1) * 64, wc = (wv & 1) * 64;
    const int c0 = tid, c1 = tid + 256;
    const int r0 = c0 >> 2, k80 = (c0 & 3) * 8;
    const int r1 = c1 >> 2, k81 = (c1 & 3) * 8;

    for (int k0 = 0; k0 < Kd; k0 += 64) {
        __syncthreads();   // protect prior iter's fragment reads
        cp16_async(A + (size_t)r0 * lda + k0 + k80,      sA0 + c0 * 8);
        cp16_async(A + (size_t)r1 * lda + k0 + k81,      sA0 + c1 * 8);
        cp16_async(A + (size_t)r0 * lda + k0 + 32 + k80, sA1 + c0 * 8);
        cp16_async(A + (size_t)r1 * lda + k0 + 32 + k81, sA1 + c1 * 8);
        cp16_async(B + (size_t)r0 * ldb + k0 + k80,      sB0 + c0 * 8);
        cp16_async(B + (size_t)r1 * ldb + k0 + k81,      sB0 + c1 * 8);
        cp16_async(B + (size_t)r0 * ldb + k0 + 32 + k80, sB1 + c0 * 8);
        cp16_async(B + (size_t)r1 * ldb + k0 + 32 + k81, sB1 + c1 * 8);
        __syncthreads();   // compiler drains vmcnt(0) here
#pragma unroll
        for (int half = 0; half < 2; ++half) {
            const short* pa = half ? sA1 : sA0;
            const short* pb = half ? sB1 : sB0;
            bf16x8 af[4], bfr[4];
#pragma unroll
            for (int i = 0; i < 4; ++i)
                af[i] = *(const bf16x8*)&pa[(wr + i * 16 + lr) * 32 + quad * 8];
#pragma unroll
            for (int j = 0; j < 4; ++j)
                bfr[j] = *(const bf16x8*)&pb[(wc + j * 16 + lr) * 32 + quad * 8];
#pragma unroll
            for (int i = 0; i < 4; ++i)
#pragma unroll
                for (int j = 0; j < 4; ++j)
                    acc[i * 4 + j] = __builtin_amdgcn_mfma_f32_16x16x32_bf16(af[i], bfr[j], acc[i * 4 + j], 0, 0, 0);
        }
    }
}

__device__ inline void store_out(float* p, float v) { *p = v; }
__device__ inline void store_out(short* p, float v) { *p = f2bf(v); }

template <typename OutT>
__device__ inline void store_tile128(OutT* C, int ldc, const f32x4* acc) {
    const int lane = threadIdx.x & 63, wv = threadIdx.x >> 6;
    const int quad = lane >> 4, lr = lane & 15;
    const int wr = (wv >> 1) * 64, wc = (wv & 1) * 64;
#pragma unroll
    for (int i = 0; i < 4; ++i)
#pragma unroll
        for (int j = 0; j < 4; ++j)
#pragma unroll
            for (int r = 0; r < 4; ++r)
                store_out(&C[(size_t)(wr + i * 16 + quad * 4 + r) * ldc + wc + j * 16 + lr],
                          acc[i * 4 + j][r]);
}

// ================= device-side phase bodies (shared by both paths) =================

__device__ inline void body_prep(int vb, const float* x, short* Xb,
                                 const float* Wq, const float* Wk,
                                 const float* Wv, const float* Wo, short* W4T) {
    const int tid = threadIdx.x;
    if (vb < 8192) {
        int i = vb * 256 + tid;
        float4 f = ((const float4*)x)[i];
        union { short s[4]; int2 v; } u;
        u.s[0] = f2bf(f.x); u.s[1] = f2bf(f.y); u.s[2] = f2bf(f.z); u.s[3] = f2bf(f.w);
        ((int2*)Xb)[i] = u.v;
    } else {
        int i = (vb - 8192) * 256 + tid;
        int w = i >> 18;
        int r = i & 262143;
        int n = r >> 9, k = r & 511;
        const float* W = (w == 0) ? Wq : (w == 1) ? Wk : (w == 2) ? Wv : Wo;
        W4T[i] = f2bf(W[k * 512 + n]);
    }
}

__device__ inline void body_proj(int vb, const short* Xb, const short* W4T,
                                 short* Qb, short* Kb, short* Vt, short* Kt,
                                 short* sA0, short* sA1, short* sB0, short* sB1) {
    const int lane = threadIdx.x & 63, wv = threadIdx.x >> 6;
    const int quad = lane >> 4, lr = lane & 15;
    const int wr = (wv >> 1) * 64, wc = (wv & 1) * 64;
    f32x4 acc[16];
#pragma unroll
    for (int i = 0; i < 16; ++i) acc[i] = (f32x4){0.f, 0.f, 0.f, 0.f};
    if (vb < 1024) {
        const int mt = vb >> 3, by = vb & 7;
        const short* At = Xb + (size_t)mt * 128 * 512;
        const short* Bt = W4T + (size_t)by * 128 * 512;   // by<4: Wq cols, else Wk cols
        short* Ct = ((by < 4) ? Qb : Kb) + (size_t)mt * 128 * 512 + (by & 3) * 128;
        mfma_kloop64(At, 512, Bt, 512, 512, acc, sA0, sA1, sB0, sB1);
        store_tile128(Ct, 512, acc);
        if (by >= 4) {   // emit Kt[b][f][t] from registers
            const int b = mt >> 5;
            const int t0b = (mt & 31) * 128;
            const int f0 = (by - 4) * 128;
#pragma unroll
            for (int i = 0; i < 4; ++i)
#pragma unroll
                for (int j = 0; j < 4; ++j) {
                    int f = f0 + wc + j * 16 + lr;
                    int tt0 = t0b + wr + i * 16 + quad * 4;
                    short tmp[4];
#pragma unroll
                    for (int r = 0; r < 4; ++r) tmp[r] = f2bf(acc[i * 4 + j][r]);
                    *(int2*)&Kt[((size_t)b * 512 + f) * 4096 + tt0] = *(const int2*)tmp;
                }
        }
    } else {
        const int r = vb - 1024;
        const int b = r & 3, tt = (r >> 2) & 31, ft = r >> 7;
        const short* At = W4T + (size_t)2 * 262144 + (size_t)ft * 128 * 512;   // Wv
        const short* Bt = Xb + ((size_t)b * 4096 + tt * 128) * 512;
        short* Ct = Vt + (size_t)b * 512 * 4096 + (size_t)ft * 128 * 4096 + tt * 128;
        mfma_kloop64(At, 512, Bt, 512, 512, acc, sA0, sA1, sB0, sB1);
        store_tile128(Ct, 4096, acc);
    }
}

__device__ inline void body_phaseA(int vb, const short* Vt, const short* Kt, short* AM,
                                   short* sA0, short* sA1, short* sB0, short* sB1) {
    const int xt = vb & 3, yt = (vb >> 2) & 3, bc = vb >> 4;
    const int b = bc >> 4, c = bc & 15;
    const short* Ap = Vt + ((size_t)b * 512 + xt * 128) * 4096 + c * 256;
    const short* Bp = Kt + ((size_t)b * 512 + yt * 128) * 4096 + c * 256;
    short* Cp = AM + (size_t)bc * 262144 + (size_t)xt * 128 * 512 + yt * 128;
    f32x4 acc[16];
#pragma unroll
    for (int i = 0; i < 16; ++i) acc[i] = (f32x4){0.f, 0.f, 0.f, 0.f};
    mfma_kloop64(Ap, 4096, Bp, 4096, 256, acc, sA0, sA1, sB0, sB1);
    store_tile128(Cp, 512, acc);
}

__device__ inline void body_scan_phaseS(int vb, short* AM, const short* Qb, const short* Kb,
                                        short* P,
                                        short* sA0, short* sA1, short* sB0, short* sB1) {
    const int tid = threadIdx.x;
    if (vb < 512) {
        int i = vb * 256 + tid;   // 0..131071
        int b = i >> 15;
        int vk8 = i & 32767;
        size_t base = (size_t)b * 16 * 262144 + (size_t)vk8 * 8;
        float acc[8];
#pragma unroll
        for (int s = 0; s < 8; ++s) acc[s] = 0.f;
        for (int c = 0; c < 16; ++c) {
            short* p = AM + base + (size_t)c * 262144;
            short in8[8];
            *(int4*)in8 = *(const int4*)p;
            short out8[8];
#pragma unroll
            for (int s = 0; s < 8; ++s) out8[s] = f2bf(acc[s]);
            *(int4*)p = *(const int4*)out8;
#pragma unroll
            for (int s = 0; s < 8; ++s) acc[s] += bf2f(in8[s]);
        }
        return;
    }
    const int e = vb - 512;               // 0..255
    const int bc = e >> 2, mt = e & 1, nt = (e >> 1) & 1;
    if (mt < nt) return;                  // dead tile (never read)
    const int b = bc >> 4, c = bc & 15;
    short* Pt = P + (size_t)bc * 65536 + (size_t)mt * 128 * 256 + nt * 128;
    const short* Ap = Qb + ((size_t)(b * 4096 + c * 256 + mt * 128)) * 512;
    const short* Bp = Kb + ((size_t)(b * 4096 + c * 256 + nt * 128)) * 512;
    f32x4 acc[16];
#pragma unroll
    for (int i = 0; i < 16; ++i) acc[i] = (f32x4){0.f, 0.f, 0.f, 0.f};
    mfma_kloop64(Ap, 512, Bp, 512, 512, acc, sA0, sA1, sB0, sB1);
    const int lane = tid & 63, wv = tid >> 6;
    const int quad = lane >> 4, lr = lane & 15;
    const int wr = (wv >> 1) * 64, wc = (wv & 1) * 64;
    const bool diag = (mt == nt);
#pragma unroll
    for (int i = 0; i < 4; ++i)
#pragma unroll
        for (int j = 0; j < 4; ++j)
#pragma unroll
            for (int r = 0; r < 4; ++r) {
                int t = wr + i * 16 + quad * 4 + r;
                int jj = wc + j * 16 + lr;
                float v = (!diag || jj <= t) ? acc[i * 4 + j][r] : 0.f;
                Pt[(size_t)t * 256 + jj] = f2bf(v);
            }
}

__device__ inline void body_phaseY(int vb, const short* Qb, const short* Mpre,
                                   const short* P, const short* Vt, short* Yb,
                                   short* sA0, short* sA1, short* sB0, short* sB1) {
    const int mt = vb & 1, nt = (vb >> 1) & 3, bc = vb >> 3;
    const int b = bc >> 4, c = bc & 15;
    f32x4 acc[16];
#pragma unroll
    for (int i = 0; i < 16; ++i) acc[i] = (f32x4){0.f, 0.f, 0.f, 0.f};
    const short* Ai = Qb + ((size_t)(b * 4096 + c * 256 + mt * 128)) * 512;
    const short* Bi = Mpre + (size_t)bc * 262144 + (size_t)nt * 128 * 512;
    mfma_kloop64(Ai, 512, Bi, 512, 512, acc, sA0, sA1, sB0, sB1);
    const short* Ap = P + (size_t)bc * 65536 + (size_t)mt * 128 * 256;
    const short* Bv = Vt + ((size_t)b * 512 + nt * 128) * 4096 + c * 256;
    mfma_kloop64(Ap, 256, Bv, 4096, (mt + 1) * 128, acc, sA0, sA1, sB0, sB1);
    short* Cp = Yb + ((size_t)(b * 4096 + c * 256 + mt * 128)) * 512 + nt * 128;
    store_tile128(Cp, 512, acc);
}

__device__ inline void body_outproj(int vb, const short* Yb, const short* W4T, float* out,
                                    short* sA0, short* sA1, short* sB0, short* sB1) {
    const int mt = vb >> 2, nt = vb & 3;
    const short* At = Yb + (size_t)mt * 128 * 512;
    const short* Bt = W4T + (size_t)3 * 262144 + (size_t)nt * 128 * 512;   // Wo
    float* Ct = out + (size_t)mt * 128 * 512 + nt * 128;
    f32x4 acc[16];
#pragma unroll
    for (int i = 0; i < 16; ++i) acc[i] = (f32x4){0.f, 0.f, 0.f, 0.f};
    mfma_kloop64(At, 512, Bt, 512, 512, acc, sA0, sA1, sB0, sB1);
    store_tile128(Ct, 512, acc);
}

// ================= cooperative fused kernel =================

__global__ __launch_bounds__(256, 2) void fused_all(
    const float* __restrict__ x,
    const float* __restrict__ Wq, const float* __restrict__ Wk,
    const float* __restrict__ Wv, const float* __restrict__ Wo,
    short* __restrict__ Xb, short* __restrict__ W4T,
    short* __restrict__ Qb, short* __restrict__ Kb,
    short* __restrict__ Kt, short* __restrict__ Vt,
    short* __restrict__ P, short* __restrict__ AM,
    float* __restrict__ out)
{
    __shared__ short sA0[4096], sA1[4096], sB0[4096], sB1[4096];
    cg::grid_group grid = cg::this_grid();
    const int nb = gridDim.x;
    short* Yb = Kb;   // Kb dead after scan_phaseS phase

    for (int vb = blockIdx.x; vb < 12288; vb += nb)
        body_prep(vb, x, Xb, Wq, Wk, Wv, Wo, W4T);
    grid.sync();
    for (int vb = blockIdx.x; vb < 1536; vb += nb)
        body_proj(vb, Xb, W4T, Qb, Kb, Vt, Kt, sA0, sA1, sB0, sB1);
    grid.sync();
    for (int vb = blockIdx.x; vb < 1024; vb += nb)
        body_phaseA(vb, Vt, Kt, AM, sA0, sA1, sB0, sB1);
    grid.sync();
    for (int vb = blockIdx.x; vb < 768; vb += nb)
        body_scan_phaseS(vb, AM, Qb, Kb, P, sA0, sA1, sB0, sB1);
    grid.sync();
    for (int vb = blockIdx.x; vb < 512; vb += nb)
        body_phaseY(vb, Qb, AM, P, Vt, Yb, sA0, sA1, sB0, sB1);
    grid.sync();
    for (int vb = blockIdx.x; vb < 512; vb += nb)
        body_outproj(vb, Yb, W4T, out, sA0, sA1, sB0, sB1);
}

// ================= fallback multi-launch kernels =================

__global__ void prep_kernel(const float* __restrict__ x, short* __restrict__ Xb,
                            const float* __restrict__ W0, const float* __restrict__ W1,
                            const float* __restrict__ W2, const float* __restrict__ W3,
                            short* __restrict__ W4T) {
    body_prep(blockIdx.x, x, Xb, W0, W1, W2, W3, W4T);
}

__global__ __launch_bounds__(256, 2) void proj_all(const short* __restrict__ Xb,
                                                   const short* __restrict__ W4T,
                                                   short* __restrict__ Qb, short* __restrict__ Kb,
                                                   short* __restrict__ Vt, short* __restrict__ Kt) {
    __shared__ short sA0[4096], sA1[4096], sB0[4096], sB1[4096];
    body_proj(blockIdx.x, Xb, W4T, Qb, Kb, Vt, Kt, sA0, sA1, sB0, sB1);
}

__global__ __launch_bounds__(256, 2) void phaseA_k(const short* __restrict__ Vt,
                                                   const short* __restrict__ Kt,
                                                   short* __restrict__ AM) {
    __shared__ short sA0[4096], sA1[4096], sB0[4096], sB1[4096];
    body_phaseA(blockIdx.x, Vt, Kt, AM, sA0, sA1, sB0, sB1);
}

__global__ __launch_bounds__(256, 2) void scan_phaseS_k(short* __restrict__ AM,
                                                        const short* __restrict__ Q,
                                                        const short* __restrict__ K,
                                                        short* __restrict__ P) {
    __shared__ short sA0[4096], sA1[4096], sB0[4096], sB1[4096];
    body_scan_phaseS(blockIdx.x, AM, Q, K, P, sA0, sA1, sB0, sB1);
}

__global__ __launch_bounds__(256, 2) void phaseY_k(const short* __restrict__ Q,
                                                   const short* __restrict__ Mpre,
                                                   const short* __restrict__ P,
                                                   const short* __restrict__ Vt,
                                                   short* __restrict__ Y) {
    __shared__ short sA0[4096], sA1[4096], sB0[4096], sB1[4096];
    body_phaseY(blockIdx.x, Q, Mpre, P, Vt, Y, sA0, sA1, sB0, sB1);
}

__global__ __launch_bounds__(256, 2) void outproj_k(const short* __restrict__ Y,
                                                    const short* __restrict__ W4T,
                                                    float* __restrict__ out) {
    __shared__ short sA0[4096], sA1[4096], sB0[4096], sB1[4096];
    body_outproj(blockIdx.x, Y, W4T, out, sA0, sA1, sB0, sB1);
}

// ---------------- host ----------------

extern "C" void kernel_launch(void* const* d_in, const int* in_sizes, int n_in,
                              void* d_out, int out_size, void* d_ws, size_t ws_size,
                              hipStream_t stream) {
    const float* x  = (const float*)d_in[0];
    const float* Wq = (const float*)d_in[1];
    const float* Wk = (const float*)d_in[2];
    const float* Wv = (const float*)d_in[3];
    const float* Wo = (const float*)d_in[4];
    float* out = (float*)d_out;

    const size_t NTD = 16384 * 512;   // 8,388,608 elems

    short* ws  = (short*)d_ws;
    short* Xb  = ws;                  // 8.39M
    short* Qb  = Xb + NTD;
    short* Kb  = Qb + NTD;
    short* Kt  = Kb + NTD;
    short* Vt  = Kt + NTD;
    short* P   = Vt + NTD;            // 4.19M
    short* W4T = P + 4194304;         // 1.05M : WqT|WkT|WvT|WoT
    short* AM  = W4T + 1048576;       // 16.78M
    short* Yb  = Kb;                  // Kb dead after scan_phaseS

    // ---- try cooperative fused launch, clamped to queried occupancy ----
    int maxb = 0;
    hipError_t qerr = hipOccupancyMaxActiveBlocksPerMultiprocessor(
        &maxb, (const void*)fused_all, 256, 0);
    hipError_t lerr = hipErrorUnknown;
    if (qerr == hipSuccess && maxb > 0) {
        int nblk = maxb * 256;
        if (nblk > 512) nblk = 512;
        void* args[] = {
            (void*)&x, (void*)&Wq, (void*)&Wk, (void*)&Wv, (void*)&Wo,
            (void*)&Xb, (void*)&W4T, (void*)&Qb, (void*)&Kb, (void*)&Kt,
            (void*)&Vt, (void*)&P, (void*)&AM, (void*)&out
        };
        lerr = hipLaunchCooperativeKernel((const void*)fused_all, dim3(nblk),
                                          dim3(256), args, 0, stream);
    }
    if (lerr == hipSuccess) return;

    // ---- fallback: proven 6-launch pipeline ----
    prep_kernel<<<12288, 256, 0, stream>>>(x, Xb, Wq, Wk, Wv, Wo, W4T);
    proj_all<<<1536, 256, 0, stream>>>(Xb, W4T, Qb, Kb, Vt, Kt);
    phaseA_k<<<1024, 256, 0, stream>>>(Vt, Kt, AM);
    scan_phaseS_k<<<768, 256, 0, stream>>>(AM, Qb, Kb, P);
    phaseY_k<<<512, 256, 0, stream>>>(Qb, AM, P, Vt, Yb);
    outproj_k<<<512, 256, 0, stream>>>(Yb, W4T, out);
}

// Round 8
// 222.119 us; speedup vs baseline: 1.9620x; 1.9620x over previous
//
#include <hip/hip_runtime.h>
#include <hip/hip_bf16.h>

typedef __attribute__((ext_vector_type(8))) short bf16x8;
typedef __attribute__((ext_vector_type(4))) float f32x4;

__device__ inline short f2bf(float f) {
    __hip_bfloat16 h = __float2bfloat16(f);
    short s;
    __builtin_memcpy(&s, &h, 2);
    return s;
}
__device__ inline float bf2f(short s) {
    unsigned int u = ((unsigned int)(unsigned short)s) << 16;
    float f;
    __builtin_memcpy(&f, &u, 4);
    return f;
}

// async 16B global->LDS; dest must be wave-uniform base + lane*16
__device__ inline void cp16_async(const void* g, void* l) {
    __builtin_amdgcn_global_load_lds(
        (const __attribute__((address_space(1))) void*)g,
        (__attribute__((address_space(3))) void*)l, 16, 0, 0);
}

// ---------------- prep: cast x + LDS-tiled transpose-cast of 4 weights ----------------
// grid 8448: blocks 0..8191 cast x (float4->bf16x4); 8192..8447 transpose W (64x64 tiles)
__global__ void prep_kernel(const float* __restrict__ x, short* __restrict__ Xb,
                            const float* __restrict__ W0, const float* __restrict__ W1,
                            const float* __restrict__ W2, const float* __restrict__ W3,
                            short* __restrict__ W4T) {
    __shared__ short sT[64][72];   // 144B rows, 16B-aligned
    const int bid = blockIdx.x, tid = threadIdx.x;
    if (bid < 8192) {
        int i = bid * 256 + tid;
        float4 f = ((const float4*)x)[i];
        union { short s[4]; int2 v; } u;
        u.s[0] = f2bf(f.x); u.s[1] = f2bf(f.y); u.s[2] = f2bf(f.z); u.s[3] = f2bf(f.w);
        ((int2*)Xb)[i] = u.v;
        return;
    }
    const int wb = bid - 8192;            // 0..255
    const int w = wb >> 6, r = wb & 63;
    const int n0 = (r >> 3) * 64, k0 = (r & 7) * 64;
    const float* W = (w == 0) ? W0 : (w == 1) ? W1 : (w == 2) ? W2 : W3;
    // read 64x64 fp32 tile coalesced (rows = k), scatter bf16 into sT[n][k]
#pragma unroll
    for (int rr = 0; rr < 4; ++rr) {
        int c = rr * 256 + tid;           // 0..1023 float4-chunks
        int row = c >> 4, col4 = (c & 15) * 4;
        float4 f = *(const float4*)&W[(size_t)(k0 + row) * 512 + n0 + col4];
        sT[col4 + 0][row] = f2bf(f.x);
        sT[col4 + 1][row] = f2bf(f.y);
        sT[col4 + 2][row] = f2bf(f.z);
        sT[col4 + 3][row] = f2bf(f.w);
    }
    __syncthreads();
    // write W4T[w][n][k] coalesced (int4 = 8 shorts)
#pragma unroll
    for (int rr = 0; rr < 2; ++rr) {
        int c = rr * 256 + tid;           // 0..511 int4-chunks
        int f = c >> 3, k8 = (c & 7) * 8;
        int4 v = *(const int4*)&sT[f][k8];
        *(int4*)&W4T[(size_t)w * 262144 + (size_t)(n0 + f) * 512 + k0 + k8] = v;
    }
}

// ---------------- 128x128 core (narrow), K-step 64 ----------------

__device__ inline void mfma_kloop64(const short* __restrict__ A, int lda,
                                    const short* __restrict__ B, int ldb,
                                    int Kd, f32x4* acc,
                                    short* sA0, short* sA1, short* sB0, short* sB1) {
    const int tid = threadIdx.x, lane = tid & 63, wv = tid >> 6;
    const int quad = lane >> 4, lr = lane & 15;
    const int wr = (wv >> 1) * 64, wc = (wv & 1) * 64;
    const int c0 = tid, c1 = tid + 256;
    const int r0 = c0 >> 2, k80 = (c0 & 3) * 8;
    const int r1 = c1 >> 2, k81 = (c1 & 3) * 8;

    for (int k0 = 0; k0 < Kd; k0 += 64) {
        __syncthreads();
        cp16_async(A + (size_t)r0 * lda + k0 + k80,      sA0 + c0 * 8);
        cp16_async(A + (size_t)r1 * lda + k0 + k81,      sA0 + c1 * 8);
        cp16_async(A + (size_t)r0 * lda + k0 + 32 + k80, sA1 + c0 * 8);
        cp16_async(A + (size_t)r1 * lda + k0 + 32 + k81, sA1 + c1 * 8);
        cp16_async(B + (size_t)r0 * ldb + k0 + k80,      sB0 + c0 * 8);
        cp16_async(B + (size_t)r1 * ldb + k0 + k81,      sB0 + c1 * 8);
        cp16_async(B + (size_t)r0 * ldb + k0 + 32 + k80, sB1 + c0 * 8);
        cp16_async(B + (size_t)r1 * ldb + k0 + 32 + k81, sB1 + c1 * 8);
        __syncthreads();
#pragma unroll
        for (int half = 0; half < 2; ++half) {
            const short* pa = half ? sA1 : sA0;
            const short* pb = half ? sB1 : sB0;
            bf16x8 af[4], bfr[4];
#pragma unroll
            for (int i = 0; i < 4; ++i)
                af[i] = *(const bf16x8*)&pa[(wr + i * 16 + lr) * 32 + quad * 8];
#pragma unroll
            for (int j = 0; j < 4; ++j)
                bfr[j] = *(const bf16x8*)&pb[(wc + j * 16 + lr) * 32 + quad * 8];
#pragma unroll
            for (int i = 0; i < 4; ++i)
#pragma unroll
                for (int j = 0; j < 4; ++j)
                    acc[i * 4 + j] = __builtin_amdgcn_mfma_f32_16x16x32_bf16(af[i], bfr[j], acc[i * 4 + j], 0, 0, 0);
        }
    }
}

__device__ inline void store_out(float* p, float v) { *p = v; }
__device__ inline void store_out(short* p, float v) { *p = f2bf(v); }

template <typename OutT>
__device__ inline void store_tile128(OutT* C, int ldc, const f32x4* acc) {
    const int lane = threadIdx.x & 63, wv = threadIdx.x >> 6;
    const int quad = lane >> 4, lr = lane & 15;
    const int wr = (wv >> 1) * 64, wc = (wv & 1) * 64;
#pragma unroll
    for (int i = 0; i < 4; ++i)
#pragma unroll
        for (int j = 0; j < 4; ++j)
#pragma unroll
            for (int r = 0; r < 4; ++r)
                store_out(&C[(size_t)(wr + i * 16 + quad * 4 + r) * ldc + wc + j * 16 + lr],
                          acc[i * 4 + j][r]);
}

// ---------------- 128x256 core (wide): wave = 64m x 128n ----------------
// reads:MFMA = 1:2.67 (vs 1:2 narrow) -> not LDS-read-bound; barriers per work halved

__device__ inline void mfma_kloop64_wide(const short* __restrict__ A, int lda,
                                         const short* __restrict__ B, int ldb,
                                         int Kd, f32x4* acc,
                                         short* sA0, short* sA1, short* sB0, short* sB1) {
    const int tid = threadIdx.x, lane = tid & 63, wv = tid >> 6;
    const int quad = lane >> 4, lr = lane & 15;
    const int wr = (wv >> 1) * 64, wc = (wv & 1) * 128;

    for (int k0 = 0; k0 < Kd; k0 += 64) {
        __syncthreads();
#pragma unroll
        for (int rr = 0; rr < 2; ++rr) {          // A: 128x32 per panel
            int c = rr * 256 + tid;
            int row = c >> 2, k8 = (c & 3) * 8;
            cp16_async(A + (size_t)row * lda + k0 + k8,      sA0 + c * 8);
            cp16_async(A + (size_t)row * lda + k0 + 32 + k8, sA1 + c * 8);
        }
#pragma unroll
        for (int rr = 0; rr < 4; ++rr) {          // B: 256x32 per panel
            int c = rr * 256 + tid;
            int row = c >> 2, k8 = (c & 3) * 8;
            cp16_async(B + (size_t)row * ldb + k0 + k8,      sB0 + c * 8);
            cp16_async(B + (size_t)row * ldb + k0 + 32 + k8, sB1 + c * 8);
        }
        __syncthreads();
#pragma unroll
        for (int half = 0; half < 2; ++half) {
            const short* pa = half ? sA1 : sA0;
            const short* pb = half ? sB1 : sB0;
            bf16x8 af[4], bfr[8];
#pragma unroll
            for (int i = 0; i < 4; ++i)
                af[i] = *(const bf16x8*)&pa[(wr + i * 16 + lr) * 32 + quad * 8];
#pragma unroll
            for (int j = 0; j < 8; ++j)
                bfr[j] = *(const bf16x8*)&pb[(wc + j * 16 + lr) * 32 + quad * 8];
#pragma unroll
            for (int i = 0; i < 4; ++i)
#pragma unroll
                for (int j = 0; j < 8; ++j)
                    acc[i * 8 + j] = __builtin_amdgcn_mfma_f32_16x16x32_bf16(af[i], bfr[j], acc[i * 8 + j], 0, 0, 0);
        }
    }
}

template <typename OutT>
__device__ inline void store_tile_wide(OutT* C, int ldc, const f32x4* acc) {
    const int lane = threadIdx.x & 63, wv = threadIdx.x >> 6;
    const int quad = lane >> 4, lr = lane & 15;
    const int wr = (wv >> 1) * 64, wc = (wv & 1) * 128;
#pragma unroll
    for (int i = 0; i < 4; ++i)
#pragma unroll
        for (int j = 0; j < 8; ++j)
#pragma unroll
            for (int r = 0; r < 4; ++r)
                store_out(&C[(size_t)(wr + i * 16 + quad * 4 + r) * ldc + wc + j * 16 + lr],
                          acc[i * 8 + j][r]);
}

#define LDS_NARROW __shared__ short sA0[4096], sA1[4096], sB0[4096], sB1[4096]
#define LDS_WIDE   __shared__ short sA0[4096], sA1[4096], sB0[8192], sB1[8192]

// ---------------- projections (wide tiles) ----------------
// grid 768: 0..511 Q|K (mt = vb>>2, ny = vb&3: ny<2 -> Q n-tile, else K n-tile; K blocks scatter Kt)
//           512..767 Vt: g -> b = g&3, tt = (g>>2)&15, ft = g>>6
__global__ __launch_bounds__(256, 2) void proj_wide(const short* __restrict__ Xb,
                                                    const short* __restrict__ W4T,
                                                    short* __restrict__ Qb, short* __restrict__ Kb,
                                                    short* __restrict__ Vt, short* __restrict__ Kt) {
    LDS_WIDE;
    f32x4 acc[32];
#pragma unroll
    for (int i = 0; i < 32; ++i) acc[i] = (f32x4){0.f, 0.f, 0.f, 0.f};
    const int vb = blockIdx.x;
    const int lane = threadIdx.x & 63, wv = threadIdx.x >> 6;
    const int quad = lane >> 4, lr = lane & 15;
    const int wr = (wv >> 1) * 64, wc = (wv & 1) * 128;
    if (vb < 512) {
        const int mt = vb >> 2, ny = vb & 3;
        const int isK = (ny >= 2), nt = ny & 1;
        const short* At = Xb + (size_t)mt * 128 * 512;
        const short* Bt = W4T + ((size_t)isK * 512 + nt * 256) * 512;
        short* Ct = (isK ? Kb : Qb) + (size_t)mt * 128 * 512 + nt * 256;
        mfma_kloop64_wide(At, 512, Bt, 512, 512, acc, sA0, sA1, sB0, sB1);
        store_tile_wide(Ct, 512, acc);
        if (isK) {   // emit Kt[b][f][t] from registers
            const int b = mt >> 5;
            const int t0b = (mt & 31) * 128;
            const int f0 = nt * 256;
#pragma unroll
            for (int i = 0; i < 4; ++i)
#pragma unroll
                for (int j = 0; j < 8; ++j) {
                    int f = f0 + wc + j * 16 + lr;
                    int tt0 = t0b + wr + i * 16 + quad * 4;
                    short tmp[4];
#pragma unroll
                    for (int r = 0; r < 4; ++r) tmp[r] = f2bf(acc[i * 8 + j][r]);
                    *(int2*)&Kt[((size_t)b * 512 + f) * 4096 + tt0] = *(const int2*)tmp;
                }
        }
    } else {
        const int g = vb - 512;
        const int b = g & 3, tt = (g >> 2) & 15, ft = g >> 6;
        const short* At = W4T + (size_t)2 * 262144 + (size_t)ft * 128 * 512;   // Wv
        const short* Bt = Xb + ((size_t)b * 4096 + tt * 256) * 512;
        short* Ct = Vt + (size_t)b * 512 * 4096 + (size_t)ft * 128 * 4096 + tt * 256;
        mfma_kloop64_wide(At, 512, Bt, 512, 512, acc, sA0, sA1, sB0, sB1);
        store_tile_wide(Ct, 4096, acc);
    }
}

// ---------------- phaseA (wide): AM[b,c][v][k] ; grid 512 ----------------
// vb -> mt = vb&3 (v-tile 128), nt = (vb>>2)&1 (k-tile 256), bc = vb>>3
__global__ __launch_bounds__(256, 2) void phaseA_wide(const short* __restrict__ Vt,
                                                      const short* __restrict__ Kt,
                                                      short* __restrict__ AM) {
    LDS_WIDE;
    const int vb = blockIdx.x;
    const int mt = vb & 3, nt = (vb >> 2) & 1, bc = vb >> 3;
    const int b = bc >> 4, c = bc & 15;
    const short* Ap = Vt + ((size_t)b * 512 + mt * 128) * 4096 + c * 256;
    const short* Bp = Kt + ((size_t)b * 512 + nt * 256) * 4096 + c * 256;
    short* Cp = AM + (size_t)bc * 262144 + (size_t)mt * 128 * 512 + nt * 256;
    f32x4 acc[32];
#pragma unroll
    for (int i = 0; i < 32; ++i) acc[i] = (f32x4){0.f, 0.f, 0.f, 0.f};
    mfma_kloop64_wide(Ap, 4096, Bp, 4096, 256, acc, sA0, sA1, sB0, sB1);
    store_tile_wide(Cp, 512, acc);
}

// ---------------- scan + phaseS (narrow) ----------------
__global__ __launch_bounds__(256, 2) void scan_phaseS_k(short* __restrict__ AM,
                                                        const short* __restrict__ Q,
                                                        const short* __restrict__ K,
                                                        short* __restrict__ P) {
    LDS_NARROW;
    const int tid = threadIdx.x;
    if (blockIdx.x < 512) {
        int i = blockIdx.x * 256 + tid;   // 0..131071
        int b = i >> 15;
        int vk8 = i & 32767;
        size_t base = (size_t)b * 16 * 262144 + (size_t)vk8 * 8;
        float acc[8];
#pragma unroll
        for (int s = 0; s < 8; ++s) acc[s] = 0.f;
        for (int c = 0; c < 16; ++c) {
            short* p = AM + base + (size_t)c * 262144;
            short in8[8];
            *(int4*)in8 = *(const int4*)p;
            short out8[8];
#pragma unroll
            for (int s = 0; s < 8; ++s) out8[s] = f2bf(acc[s]);
            *(int4*)p = *(const int4*)out8;
#pragma unroll
            for (int s = 0; s < 8; ++s) acc[s] += bf2f(in8[s]);
        }
        return;
    }
    const int e = blockIdx.x - 512;       // 0..255
    const int bc = e >> 2, mt = e & 1, nt = (e >> 1) & 1;
    if (mt < nt) return;                  // dead tile (never read)
    const int b = bc >> 4, c = bc & 15;
    short* Pt = P + (size_t)bc * 65536 + (size_t)mt * 128 * 256 + nt * 128;
    const short* Ap = Q + ((size_t)(b * 4096 + c * 256 + mt * 128)) * 512;
    const short* Bp = K + ((size_t)(b * 4096 + c * 256 + nt * 128)) * 512;
    f32x4 acc[16];
#pragma unroll
    for (int i = 0; i < 16; ++i) acc[i] = (f32x4){0.f, 0.f, 0.f, 0.f};
    mfma_kloop64(Ap, 512, Bp, 512, 512, acc, sA0, sA1, sB0, sB1);
    const int lane = tid & 63, wv = tid >> 6;
    const int quad = lane >> 4, lr = lane & 15;
    const int wr = (wv >> 1) * 64, wc = (wv & 1) * 64;
    const bool diag = (mt == nt);
#pragma unroll
    for (int i = 0; i < 4; ++i)
#pragma unroll
        for (int j = 0; j < 4; ++j)
#pragma unroll
            for (int r = 0; r < 4; ++r) {
                int t = wr + i * 16 + quad * 4 + r;
                int jj = wc + j * 16 + lr;
                float v = (!diag || jj <= t) ? acc[i * 4 + j][r] : 0.f;
                Pt[(size_t)t * 256 + jj] = f2bf(v);
            }
}

// ---------------- phaseY (narrow) ----------------
__global__ __launch_bounds__(256, 2) void phaseY_k(const short* __restrict__ Q,
                                                   const short* __restrict__ Mpre,
                                                   const short* __restrict__ P,
                                                   const short* __restrict__ Vt,
                                                   short* __restrict__ Y) {
    LDS_NARROW;
    const int vb = blockIdx.x;
    const int mt = vb & 1, nt = (vb >> 1) & 3, bc = vb >> 3;
    const int b = bc >> 4, c = bc & 15;
    f32x4 acc[16];
#pragma unroll
    for (int i = 0; i < 16; ++i) acc[i] = (f32x4){0.f, 0.f, 0.f, 0.f};
    const short* Ai = Q + ((size_t)(b * 4096 + c * 256 + mt * 128)) * 512;
    const short* Bi = Mpre + (size_t)bc * 262144 + (size_t)nt * 128 * 512;
    mfma_kloop64(Ai, 512, Bi, 512, 512, acc, sA0, sA1, sB0, sB1);
    const short* Ap = P + (size_t)bc * 65536 + (size_t)mt * 128 * 256;
    const short* Bv = Vt + ((size_t)b * 512 + nt * 128) * 4096 + c * 256;
    mfma_kloop64(Ap, 256, Bv, 4096, (mt + 1) * 128, acc, sA0, sA1, sB0, sB1);
    short* Cp = Y + ((size_t)(b * 4096 + c * 256 + mt * 128)) * 512 + nt * 128;
    store_tile128(Cp, 512, acc);
}

// ---------------- output projection (narrow) ----------------
__global__ __launch_bounds__(256, 2) void outproj_k(const short* __restrict__ Y,
                                                    const short* __restrict__ W4T,
                                                    float* __restrict__ out) {
    LDS_NARROW;
    const int mt = blockIdx.x >> 2, nt = blockIdx.x & 3;
    const short* At = Y + (size_t)mt * 128 * 512;
    const short* Bt = W4T + (size_t)3 * 262144 + (size_t)nt * 128 * 512;   // Wo
    float* Ct = out + (size_t)mt * 128 * 512 + nt * 128;
    f32x4 acc[16];
#pragma unroll
    for (int i = 0; i < 16; ++i) acc[i] = (f32x4){0.f, 0.f, 0.f, 0.f};
    mfma_kloop64(At, 512, Bt, 512, 512, acc, sA0, sA1, sB0, sB1);
    store_tile128(Ct, 512, acc);
}

// ---------------- host ----------------

extern "C" void kernel_launch(void* const* d_in, const int* in_sizes, int n_in,
                              void* d_out, int out_size, void* d_ws, size_t ws_size,
                              hipStream_t stream) {
    const float* x  = (const float*)d_in[0];
    const float* Wq = (const float*)d_in[1];
    const float* Wk = (const float*)d_in[2];
    const float* Wv = (const float*)d_in[3];
    const float* Wo = (const float*)d_in[4];
    float* out = (float*)d_out;

    const size_t NTD = 16384 * 512;   // 8,388,608 elems

    short* ws  = (short*)d_ws;
    short* Xb  = ws;                  // 8.39M
    short* Qb  = Xb + NTD;
    short* Kb  = Qb + NTD;
    short* Kt  = Kb + NTD;
    short* Vt  = Kt + NTD;
    short* P   = Vt + NTD;            // 4.19M
    short* W4T = P + 4194304;         // 1.05M : WqT|WkT|WvT|WoT
    short* AM  = W4T + 1048576;       // 16.78M
    short* Yb  = Kb;                  // Kb dead after scan_phaseS

    prep_kernel<<<8448, 256, 0, stream>>>(x, Xb, Wq, Wk, Wv, Wo, W4T);
    proj_wide<<<768, 256, 0, stream>>>(Xb, W4T, Qb, Kb, Vt, Kt);
    phaseA_wide<<<512, 256, 0, stream>>>(Vt, Kt, AM);
    scan_phaseS_k<<<768, 256, 0, stream>>>(AM, Qb, Kb, P);
    phaseY_k<<<512, 256, 0, stream>>>(Qb, AM, P, Vt, Yb);
    outproj_k<<<512, 256, 0, stream>>>(Yb, W4T, out);
}